// Round 2
// baseline (319.555 us; speedup 1.0000x reference)
//
#include <hip/hip_runtime.h>

// UpsampleRFFT = zero-insert 2x upsample + ideal half-band low-pass (circular),
// computed in closed form as three 128x128x128 GEMMs on MFMA:
//   g[j] = sign*cot(pi*(2j+1)/256)/128, sign=+ if j even
//   G[p][m] = g[(p-m)&127]
//   out[2r][2i]     = x[r][i]
//   out[2r][2i+1]   = T[r][i],  T = X*G   (W-conv)
//   out[2p+1][2i]   = U[p][i],  U = G*X   (H-conv)
//   out[2p+1][2i+1] = V[p][i],  V = U*G
// All tap fragments collapse to 8 unique register frags (offset (n-2t)&7).
// Lane<->k mapping is used consistently for A and B so HW k-permutation cancels.

typedef __bf16 bf16x8 __attribute__((ext_vector_type(8)));
typedef float  f32x4  __attribute__((ext_vector_type(4)));

#define PITCH 136   // ushort pitch: 272B rows keep 16B alignment, spread banks
#define NT    512

__device__ __forceinline__ unsigned short f2bf(float x) {
    unsigned int b = __float_as_uint(x);
    return (unsigned short)((b + 0x7FFFu + ((b >> 16) & 1u)) >> 16);  // RNE
}
__device__ __forceinline__ float bf2f(unsigned short u) {
    return __uint_as_float(((unsigned int)u) << 16);
}

__global__ __launch_bounds__(NT, 4)
void upsample_rfft_mfma(const float* __restrict__ xin, float* __restrict__ out)
{
    __shared__ __align__(16) unsigned short Xn[128 * PITCH];  // X natural [r][m]
    __shared__ __align__(16) unsigned short XU[128 * PITCH];  // X^T, later U
    __shared__ float g2f[128];

    const int tid  = threadIdx.x;
    const int lane = tid & 63;
    const int w    = tid >> 6;      // wave 0..7 = M-tile
    const int l15  = lane & 15;
    const int l4   = lane >> 4;     // 0..3

    const float* __restrict__ xim = xin + (long long)blockIdx.x * (128 * 128);
    float*       __restrict__ oim = out + (long long)blockIdx.x * (256 * 256);

    // ---- issue global loads early (hide latency under tap build) ----
    float4 xv[8];
    {
        const float4* xi4 = (const float4*)xim;
        #pragma unroll
        for (int k = 0; k < 8; ++k) xv[k] = xi4[k * NT + tid];
    }

    // ---- tap table ----
    if (tid < 128) {
        int d = 2 * tid + 1;
        float th = 3.14159265358979323846f * (float)d * (1.0f / 256.0f);
        float s  = ((d & 3) == 1) ? 1.0f : -1.0f;
        g2f[tid] = s * cosf(th) / (128.0f * sinf(th));
    }
    __syncthreads();

    // ---- 8 unique tap fragments (B-role: g[(col-k)&127]; A-role: g[(row-k)&127]) ----
    bf16x8 gh[8];
    #pragma unroll
    for (int dd = 0; dd < 8; ++dd) {
        union { bf16x8 v; unsigned short u[8]; } H;
        int base = l15 - 8 * l4 + 16 * dd;
        #pragma unroll
        for (int e = 0; e < 8; ++e) H.u[e] = f2bf(g2f[(base - e) & 127]);
        gh[dd] = H.v;
    }

    // ---- Xn fill (bf16) ----
    #pragma unroll
    for (int k = 0; k < 8; ++k) {
        int fidx = k * NT + tid;
        int row  = fidx >> 5;
        int c4   = (fidx & 31) << 2;
        ushort4 p;
        p.x = f2bf(xv[k].x); p.y = f2bf(xv[k].y);
        p.z = f2bf(xv[k].z); p.w = f2bf(xv[k].w);
        *(ushort4*)&Xn[row * PITCH + c4] = p;
    }
    __syncthreads();   // Xn ready

    // ---- X^T fill into XU (lane-major in c: conflict-light) ----
    {
        int c   = tid & 127;
        int mb0 = tid >> 7;
        #pragma unroll
        for (int it = 0; it < 8; ++it) {
            int m0 = 4 * (mb0 + 4 * it);
            ushort4 q;
            q.x = Xn[(m0 + 0) * PITCH + c];
            q.y = Xn[(m0 + 1) * PITCH + c];
            q.z = Xn[(m0 + 2) * PITCH + c];
            q.w = Xn[(m0 + 3) * PITCH + c];
            *(ushort4*)&XU[c * PITCH + m0] = q;
        }
    }

    // ---- pass T: T = X*G ; store even output rows {x, T} ----
    {
        bf16x8 xa[4];
        #pragma unroll
        for (int t = 0; t < 4; ++t)
            xa[t] = *(const bf16x8*)&Xn[(16 * w + l15) * PITCH + 32 * t + 8 * l4];
        #pragma unroll
        for (int n = 0; n < 8; ++n) {
            f32x4 acc = {0.f, 0.f, 0.f, 0.f};
            #pragma unroll
            for (int t = 0; t < 4; ++t)
                acc = __builtin_amdgcn_mfma_f32_16x16x32_bf16(xa[t], gh[(n - 2 * t) & 7], acc, 0, 0, 0);
            int i = 16 * n + l15;
            #pragma unroll
            for (int q = 0; q < 4; ++q) {
                int r = 16 * w + 4 * l4 + q;
                float2 o;
                o.x = bf2f(Xn[r * PITCH + i]);   // exact copy path (bf16-rounded)
                o.y = acc[q];
                *(float2*)&oim[(2 * r) * 256 + 2 * i] = o;
            }
        }
    }
    __syncthreads();   // XU = X^T ready

    // ---- pass U: U = G*X (B-frags from XU) ----
    f32x4 uacc[8];
    #pragma unroll
    for (int n = 0; n < 8; ++n) {
        f32x4 acc = {0.f, 0.f, 0.f, 0.f};
        #pragma unroll
        for (int t = 0; t < 4; ++t) {
            bf16x8 xb = *(const bf16x8*)&XU[(16 * n + l15) * PITCH + 32 * t + 8 * l4];
            acc = __builtin_amdgcn_mfma_f32_16x16x32_bf16(gh[(w - 2 * t) & 7], xb, acc, 0, 0, 0);
        }
        uacc[n] = acc;
    }
    __syncthreads();   // all waves done READING XU

    // ---- write U (bf16) into XU for pass V A-frags ----
    #pragma unroll
    for (int n = 0; n < 8; ++n) {
        int i = 16 * n + l15;
        #pragma unroll
        for (int q = 0; q < 4; ++q)
            XU[(16 * w + 4 * l4 + q) * PITCH + i] = f2bf(uacc[n][q]);
    }
    __syncthreads();   // U ready

    // ---- pass V: V = U*G ; store odd output rows {U(fp32 regs), V} ----
    {
        bf16x8 ua[4];
        #pragma unroll
        for (int t = 0; t < 4; ++t)
            ua[t] = *(const bf16x8*)&XU[(16 * w + l15) * PITCH + 32 * t + 8 * l4];
        #pragma unroll
        for (int n = 0; n < 8; ++n) {
            f32x4 acc = {0.f, 0.f, 0.f, 0.f};
            #pragma unroll
            for (int t = 0; t < 4; ++t)
                acc = __builtin_amdgcn_mfma_f32_16x16x32_bf16(ua[t], gh[(n - 2 * t) & 7], acc, 0, 0, 0);
            int i = 16 * n + l15;
            #pragma unroll
            for (int q = 0; q < 4; ++q) {
                int p = 16 * w + 4 * l4 + q;
                float2 o;
                o.x = uacc[n][q];
                o.y = acc[q];
                *(float2*)&oim[(2 * p + 1) * 256 + 2 * i] = o;
            }
        }
    }
}

extern "C" void kernel_launch(void* const* d_in, const int* in_sizes, int n_in,
                              void* d_out, int out_size, void* d_ws, size_t ws_size,
                              hipStream_t stream)
{
    (void)n_in; (void)out_size; (void)d_ws; (void)ws_size;
    const float* x = (const float*)d_in[0];
    float* out = (float*)d_out;
    int nimg = in_sizes[0] / (128 * 128);   // 1024 images
    hipLaunchKernelGGL(upsample_rfft_mfma, dim3(nimg), dim3(NT), 0, stream, x, out);
}

// Round 3
// 261.543 us; speedup vs baseline: 1.2218x; 1.2218x over previous
//
#include <hip/hip_runtime.h>

// UpsampleRFFT (zero-insert 2x + ideal half-band low-pass, circular) in closed
// form, two streaming kernels:
//   g[j] = sign*cot(pi*(2j+1)/256)/128, sign=+ if j even; g[j]=g[127-j]
//   K1: out[2r][2i]=x[r][i] (exact fp32), out[2r][2i+1]=T[r][i], T=X*G,
//       computed transposed (T^T = G^T * X^T) so lanes hold consecutive cols.
//   K2: out[2p+1][c] = sum_m g[(p-m)&127] * out[2m][c]  (GEMM over even rows)
// All tap fragments = 8 register frags gh[dd]: value g[(own - k)&127],
// own = 16*tile + l15, k = 32t + 8*l4 + e  (R2-verified lane/k convention).

typedef __bf16 bf16x8 __attribute__((ext_vector_type(8)));
typedef float  f32x4  __attribute__((ext_vector_type(4)));

#define PITCH 136   // ushort pitch for Et: 272B rows keep 16B alignment

__device__ __forceinline__ unsigned short f2bf(float x) {
    unsigned int b = __float_as_uint(x);
    return (unsigned short)((b + 0x7FFFu + ((b >> 16) & 1u)) >> 16);  // RNE
}

__device__ __forceinline__ void build_gtab(float* gtab, int tid) {
    if (tid < 128) {
        int d = 2 * tid + 1;
        float th = 3.14159265358979323846f * (float)d * (1.0f / 256.0f);
        float s  = ((d & 3) == 1) ? 1.0f : -1.0f;
        gtab[tid] = s * cosf(th) / (128.0f * sinf(th));
    }
}

__device__ __forceinline__ void build_gh(bf16x8* gh, const float* gtab, int l15, int l4) {
    #pragma unroll
    for (int dd = 0; dd < 8; ++dd) {
        union { bf16x8 v; unsigned short u[8]; } H;
        int base = l15 - 8 * l4 + 16 * dd;
        #pragma unroll
        for (int e = 0; e < 8; ++e) H.u[e] = f2bf(gtab[(base - e) & 127]);
        gh[dd] = H.v;
    }
}

// ---- K1: even output rows. grid = 2*nimg blocks x 256 thr (4 waves) ----
__global__ __launch_bounds__(256)
void k1_even(const float* __restrict__ xin, float* __restrict__ out)
{
    __shared__ float gtab[128];
    const int tid  = threadIdx.x;
    const int lane = tid & 63;
    const int w    = tid >> 6;                    // 0..3
    const int l15  = lane & 15;
    const int l4   = lane >> 4;

    const long long img = blockIdx.x >> 1;
    const int ntile = 4 * (int)(blockIdx.x & 1) + w;   // r-tile 0..7
    const float* __restrict__ xim = xin + img * (128LL * 128LL);
    float* __restrict__ oim = out + img * (256LL * 256LL);

    const int r = 16 * ntile + l15;
    const float* __restrict__ xrow = xim + r * 128;

    // B-frags (X^T): row reads, issued before tap build to hide latency
    float4 xlo[4], xhi[4];
    #pragma unroll
    for (int t = 0; t < 4; ++t) {
        xlo[t] = *(const float4*)&xrow[32 * t + 8 * l4];
        xhi[t] = *(const float4*)&xrow[32 * t + 8 * l4 + 4];
    }

    build_gtab(gtab, tid);
    __syncthreads();

    bf16x8 gh[8];
    build_gh(gh, gtab, l15, l4);

    bf16x8 xa[4];
    #pragma unroll
    for (int t = 0; t < 4; ++t) {
        union { bf16x8 v; unsigned short u[8]; } H;
        H.u[0] = f2bf(xlo[t].x); H.u[1] = f2bf(xlo[t].y);
        H.u[2] = f2bf(xlo[t].z); H.u[3] = f2bf(xlo[t].w);
        H.u[4] = f2bf(xhi[t].x); H.u[5] = f2bf(xhi[t].y);
        H.u[6] = f2bf(xhi[t].z); H.u[7] = f2bf(xhi[t].w);
        xa[t] = H.v;
    }

    float* __restrict__ orow = oim + (2 * r) * 256;
    #pragma unroll
    for (int mt = 0; mt < 8; ++mt) {
        f32x4 acc = {0.f, 0.f, 0.f, 0.f};
        #pragma unroll
        for (int t = 0; t < 4; ++t)
            acc = __builtin_amdgcn_mfma_f32_16x16x32_bf16(gh[(mt - 2 * t) & 7], xa[t], acc, 0, 0, 0);
        // lane holds T[r][i0..i0+3], i0 = 16*mt + 4*l4; x copies exact fp32
        const int i0 = 16 * mt + 4 * l4;
        float4 xc = *(const float4*)&xrow[i0];
        float4 o0 = make_float4(xc.x, acc[0], xc.y, acc[1]);
        float4 o1 = make_float4(xc.z, acc[2], xc.w, acc[3]);
        *(float4*)&orow[2 * i0]     = o0;
        *(float4*)&orow[2 * i0 + 4] = o1;
    }
}

// ---- K2: odd output rows from even rows. grid = 4*nimg blocks x 256 thr ----
__global__ __launch_bounds__(256)
void k2_odd(float* __restrict__ out)
{
    __shared__ __align__(16) unsigned short Et[64 * PITCH];  // Et[c][m] = E[m][cbase+c]
    __shared__ float gtab[128];
    const int tid = threadIdx.x;

    build_gtab(gtab, tid);

    const long long img = blockIdx.x >> 2;
    const int cbase = 64 * (int)(blockIdx.x & 3);
    float* __restrict__ oim = out + img * (256LL * 256LL);

    // stage even-row strip transposed, bf16
    {
        const int mrow = tid >> 4;
        const int c4   = (tid & 15) * 4;
        #pragma unroll
        for (int it = 0; it < 8; ++it) {
            int m = 16 * it + mrow;
            float4 v = *(const float4*)&oim[(2 * m) * 256 + cbase + c4];
            Et[(c4 + 0) * PITCH + m] = f2bf(v.x);
            Et[(c4 + 1) * PITCH + m] = f2bf(v.y);
            Et[(c4 + 2) * PITCH + m] = f2bf(v.z);
            Et[(c4 + 3) * PITCH + m] = f2bf(v.w);
        }
    }
    __syncthreads();

    const int lane = tid & 63;
    const int w    = tid >> 6;
    const int l15  = lane & 15;
    const int l4   = lane >> 4;

    bf16x8 gh[8];
    build_gh(gh, gtab, l15, l4);

    #pragma unroll
    for (int pt = 0; pt < 2; ++pt) {
        const int ptile = w + 4 * pt;                 // p-tile 0..7
        float* __restrict__ orow = oim + (2 * (16 * ptile + l15) + 1) * 256 + cbase;
        #pragma unroll
        for (int mc = 0; mc < 4; ++mc) {
            f32x4 acc = {0.f, 0.f, 0.f, 0.f};
            #pragma unroll
            for (int t = 0; t < 4; ++t) {
                bf16x8 ef = *(const bf16x8*)&Et[(16 * mc + l15) * PITCH + 32 * t + 8 * l4];
                acc = __builtin_amdgcn_mfma_f32_16x16x32_bf16(ef, gh[(ptile - 2 * t) & 7], acc, 0, 0, 0);
            }
            // lane holds odd[p][c0..c0+3], c0 = 16*mc + 4*l4
            float4 o = make_float4(acc[0], acc[1], acc[2], acc[3]);
            *(float4*)&orow[16 * mc + 4 * l4] = o;
        }
    }
}

extern "C" void kernel_launch(void* const* d_in, const int* in_sizes, int n_in,
                              void* d_out, int out_size, void* d_ws, size_t ws_size,
                              hipStream_t stream)
{
    (void)n_in; (void)out_size; (void)d_ws; (void)ws_size;
    const float* x = (const float*)d_in[0];
    float* out = (float*)d_out;
    int nimg = in_sizes[0] / (128 * 128);   // 1024 images
    hipLaunchKernelGGL(k1_even, dim3(nimg * 2), dim3(256), 0, stream, x, out);
    hipLaunchKernelGGL(k2_odd,  dim3(nimg * 4), dim3(256), 0, stream, out);
}

// Round 4
// 105.909 us; speedup vs baseline: 3.0173x; 2.4695x over previous
//
#include <hip/hip_runtime.h>

// UpsampleRFFT (zero-insert 2x + ideal half-band low-pass, circular), closed form:
//   g[j] = sign*cot(pi*(2j+1)/256)/128, sign=+ if j even
//   out[2r][2i]   = x[r][i] (exact fp32)      out[2r][2i+1] = T[r][i],  T = X*G
//   out[2p+1][c]  = sum_m g[(p-m)&127] * E[m][c],  E = even rows
// One fused kernel per image: Phase A computes T (MFMA, row-resident X), writes
// even rows to global AND E^T (bf16) to LDS; Phase B GEMMs E^T against the taps.
// Tap fragments (8 per lane, shared by A/B roles) are precomputed into d_ws.

typedef __bf16 bf16x8 __attribute__((ext_vector_type(8)));
typedef float  f32x4  __attribute__((ext_vector_type(4)));

#define W2 136        // Et ushort pitch: 272B rows, 16B-aligned
#define PI_F 3.14159265358979323846f

__device__ __forceinline__ unsigned short f2bf(float x) {
    unsigned int b = __float_as_uint(x);
    return (unsigned short)((b + 0x7FFFu + ((b >> 16) & 1u)) >> 16);  // RNE
}

__device__ __forceinline__ float gfun(int j) {           // g[j & 127]
    int d = 2 * (j & 127) + 1;
    float th = PI_F * (float)d * (1.0f / 256.0f);
    float s  = ((d & 3) == 1) ? 1.0f : -1.0f;
    return s * cosf(th) / (128.0f * sinf(th));
}

// ---- init: per-lane tap fragment table (8 frags x 64 lanes x 8 bf16 = 8KB) ----
__global__ __launch_bounds__(512)
void init_ghtab(unsigned short* __restrict__ ghtab)
{
    const int t   = threadIdx.x;          // t = dd*64 + lane
    const int lane = t & 63;
    const int l15 = lane & 15;
    const int l4  = lane >> 4;
    const int dd  = t >> 6;
    const int base = l15 - 8 * l4 + 16 * dd;
    unsigned short u[8];
    #pragma unroll
    for (int e = 0; e < 8; ++e) u[e] = f2bf(gfun(base - e));
    ushort4 a = make_ushort4(u[0], u[1], u[2], u[3]);
    ushort4 b = make_ushort4(u[4], u[5], u[6], u[7]);
    *(ushort4*)&ghtab[t * 8]     = a;
    *(ushort4*)&ghtab[t * 8 + 4] = b;
}

// ---- fused per-image kernel: 512 threads (8 waves) ----
__global__ __launch_bounds__(512, 4)
void upsample_fused(const float* __restrict__ xin, float* __restrict__ out,
                    const unsigned short* __restrict__ ghtab)
{
    __shared__ __align__(16) unsigned short Et[256 * W2];  // Et[c][m] = E[m][c], bf16
    __shared__ float gtab[128];                            // fallback only

    const int tid  = threadIdx.x;
    const int lane = tid & 63;
    const int w    = tid >> 6;        // 0..7: r-tile (phase A) and p-tile (phase B)
    const int l15  = lane & 15;
    const int l4   = lane >> 4;

    const float* __restrict__ xim = xin + (long long)blockIdx.x * (128 * 128);
    float*       __restrict__ oim = out + (long long)blockIdx.x * (256 * 256);

    const int r = 16 * w + l15;
    const float* __restrict__ xrow = xim + r * 128;

    // issue x row-slice loads first (each row covered by its 4 l4-lanes)
    float4 xlo[4], xhi[4];
    #pragma unroll
    for (int t = 0; t < 4; ++t) {
        xlo[t] = *(const float4*)&xrow[32 * t + 8 * l4];
        xhi[t] = *(const float4*)&xrow[32 * t + 8 * l4 + 4];
    }

    // tap fragments: fast path = 8 coalesced 16B loads from precomputed table
    bf16x8 gh[8];
    if (ghtab) {
        #pragma unroll
        for (int dd = 0; dd < 8; ++dd)
            gh[dd] = *(const bf16x8*)&ghtab[(dd * 64 + lane) * 8];
    } else {
        if (tid < 128) gtab[tid] = gfun(tid);
        __syncthreads();
        #pragma unroll
        for (int dd = 0; dd < 8; ++dd) {
            union { bf16x8 v; unsigned short u[8]; } H;
            int base = l15 - 8 * l4 + 16 * dd;
            #pragma unroll
            for (int e = 0; e < 8; ++e) H.u[e] = f2bf(gtab[(base - e) & 127]);
            gh[dd] = H.v;
        }
    }

    // build X fragments (bf16) and drop even columns of E^T into LDS
    bf16x8 xa[4];
    #pragma unroll
    for (int t = 0; t < 4; ++t) {
        union { bf16x8 v; unsigned short u[8]; } H;
        H.u[0] = f2bf(xlo[t].x); H.u[1] = f2bf(xlo[t].y);
        H.u[2] = f2bf(xlo[t].z); H.u[3] = f2bf(xlo[t].w);
        H.u[4] = f2bf(xhi[t].x); H.u[5] = f2bf(xhi[t].y);
        H.u[6] = f2bf(xhi[t].z); H.u[7] = f2bf(xhi[t].w);
        xa[t] = H.v;
        const int m0 = 32 * t + 8 * l4;
        #pragma unroll
        for (int e = 0; e < 8; ++e)
            Et[(2 * (m0 + e)) * W2 + r] = H.u[e];
    }

    // ---- phase A: T = X*G (transposed GEMM); even output rows + odd cols of E^T ----
    float* __restrict__ orow = oim + (2 * r) * 256;
    #pragma unroll
    for (int mt = 0; mt < 8; ++mt) {
        f32x4 acc = {0.f, 0.f, 0.f, 0.f};
        #pragma unroll
        for (int t = 0; t < 4; ++t)
            acc = __builtin_amdgcn_mfma_f32_16x16x32_bf16(gh[(mt - 2 * t) & 7], xa[t], acc, 0, 0, 0);
        const int i0 = 16 * mt + 4 * l4;              // lane holds T[r][i0..i0+3]
        float4 xc = *(const float4*)&xrow[i0];        // L1 hit (exact fp32 copies)
        float4 o0 = make_float4(xc.x, acc[0], xc.y, acc[1]);
        float4 o1 = make_float4(xc.z, acc[2], xc.w, acc[3]);
        *(float4*)&orow[2 * i0]     = o0;
        *(float4*)&orow[2 * i0 + 4] = o1;
        #pragma unroll
        for (int q = 0; q < 4; ++q)
            Et[(2 * (i0 + q) + 1) * W2 + r] = f2bf(acc[q]);
    }
    __syncthreads();

    // ---- phase B: odd[p][c] = sum_m g[(p-m)&127] * E[m][c], E^T from LDS ----
    {
        float* __restrict__ prow = oim + (2 * (16 * w + l15) + 1) * 256;
        #pragma unroll
        for (int mc = 0; mc < 16; ++mc) {
            f32x4 acc = {0.f, 0.f, 0.f, 0.f};
            #pragma unroll
            for (int t = 0; t < 4; ++t) {
                bf16x8 ef = *(const bf16x8*)&Et[(16 * mc + l15) * W2 + 32 * t + 8 * l4];
                acc = __builtin_amdgcn_mfma_f32_16x16x32_bf16(ef, gh[(w - 2 * t) & 7], acc, 0, 0, 0);
            }
            float4 o = make_float4(acc[0], acc[1], acc[2], acc[3]);
            *(float4*)&prow[16 * mc + 4 * l4] = o;    // lane holds odd[p][c0..c0+3]
        }
    }
}

extern "C" void kernel_launch(void* const* d_in, const int* in_sizes, int n_in,
                              void* d_out, int out_size, void* d_ws, size_t ws_size,
                              hipStream_t stream)
{
    (void)n_in; (void)out_size;
    const float* x = (const float*)d_in[0];
    float* out = (float*)d_out;
    int nimg = in_sizes[0] / (128 * 128);   // 1024 images

    unsigned short* ghtab = nullptr;
    if (ws_size >= 8192) {
        ghtab = (unsigned short*)d_ws;
        hipLaunchKernelGGL(init_ghtab, dim3(1), dim3(512), 0, stream, ghtab);
    }
    hipLaunchKernelGGL(upsample_fused, dim3(nimg), dim3(512), 0, stream, x, out, ghtab);
}